// Round 4
// baseline (1260.191 us; speedup 1.0000x reference)
//
#include <hip/hip_runtime.h>

#define N_NODES 50000
#define N_EDGES 800000
#define EBLK 32

typedef __attribute__((ext_vector_type(8))) short bf16x8;
typedef __attribute__((ext_vector_type(4))) float f32x4;
typedef __attribute__((ext_vector_type(2))) float f32x2;

__device__ __forceinline__ float bf2f(unsigned short u) {
  union { unsigned int u; float f; } c; c.u = ((unsigned int)u) << 16; return c.f;
}
// round-half-up: same half-ulp error bound as RNE (differs only on exact ties)
__device__ __forceinline__ unsigned short f2bf(float f) {
  union { float f; unsigned int u; } c; c.f = f;
  return (unsigned short)((c.u + 0x8000u) >> 16);
}
__device__ __forceinline__ float sspf(float x) {
  return fmaxf(x, 0.0f) + __logf(1.0f + __expf(-fabsf(x))) - 0.69314718055994531f;
}
__device__ __forceinline__ f32x4 MFMA(bf16x8 a, bf16x8 b, f32x4 c) {
  return __builtin_amdgcn_mfma_f32_16x16x32_bf16(a, b, c, 0, 0, 0);
}
__device__ __forceinline__ f32x4 f4zero() { f32x4 z = {0.f, 0.f, 0.f, 0.f}; return z; }

__device__ __forceinline__ bf16x8 cvt8(const float* __restrict__ p) {
  f32x4 x0 = *(const f32x4*)p;
  f32x4 x1 = *(const f32x4*)(p + 4);
  bf16x8 t;
  t[0] = (short)f2bf(x0[0]); t[1] = (short)f2bf(x0[1]);
  t[2] = (short)f2bf(x0[2]); t[3] = (short)f2bf(x0[3]);
  t[4] = (short)f2bf(x1[0]); t[5] = (short)f2bf(x1[1]);
  t[6] = (short)f2bf(x1[2]); t[7] = (short)f2bf(x1[3]);
  return t;
}

// ---------------------------------------------------------------------------
// Generic GEMM: Out[M,256] = act(A[M,256] @ W[256,256] + bias)
// ---------------------------------------------------------------------------
template<int ADT, int ACT, int ODT>
__global__ __launch_bounds__(256) void gemm_k256(
    const void* __restrict__ Av, const unsigned short* __restrict__ Wt,
    const float* __restrict__ bias, void* __restrict__ Outv, int M)
{
  const int m0  = (int)blockIdx.x * 64;
  const int tid = (int)threadIdx.x;
  const int w   = tid >> 6;
  const int l   = tid & 63;
  const int lr  = l & 15;
  const int g   = l >> 4;

  f32x4 acc[4][4];
#pragma unroll
  for (int a = 0; a < 4; ++a)
#pragma unroll
    for (int b = 0; b < 4; ++b) acc[a][b] = f4zero();

#pragma unroll
  for (int ks = 0; ks < 8; ++ks) {
    const int kb = ks * 32 + g * 8;
    bf16x8 af[4], bfr[4];
#pragma unroll
    for (int mf = 0; mf < 4; ++mf) {
      int row = m0 + mf * 16 + lr;
      if (row >= M) row = M - 1;
      if (ADT == 0)
        af[mf] = *(const bf16x8*)((const unsigned short*)Av + (size_t)row * 256 + kb);
      else
        af[mf] = cvt8((const float*)Av + (size_t)row * 256 + kb);
    }
#pragma unroll
    for (int nf = 0; nf < 4; ++nf) {
      const int col = w * 64 + nf * 16 + lr;
      bfr[nf] = *(const bf16x8*)(Wt + (size_t)col * 256 + kb);
    }
#pragma unroll
    for (int mf = 0; mf < 4; ++mf)
#pragma unroll
      for (int nf = 0; nf < 4; ++nf)
        acc[mf][nf] = MFMA(af[mf], bfr[nf], acc[mf][nf]);
  }

#pragma unroll
  for (int nf = 0; nf < 4; ++nf) {
    const int col = w * 64 + nf * 16 + lr;
    const float bs = bias[col];
#pragma unroll
    for (int mf = 0; mf < 4; ++mf) {
#pragma unroll
      for (int i = 0; i < 4; ++i) {
        const int row = m0 + mf * 16 + g * 4 + i;
        if (row < M) {
          float x = acc[mf][nf][i] + bs;
          if (ACT) x = sspf(x);
          if (ODT == 0)
            ((unsigned short*)Outv)[(size_t)row * 256 + col] = f2bf(x);
          else
            ((float*)Outv)[(size_t)row * 256 + col] = x;
        }
      }
    }
  }
}

// ---------------------------------------------------------------------------
// Counting sort of edges by dst + sorted-order edge metadata.
// ---------------------------------------------------------------------------
__global__ __launch_bounds__(256) void hist_dst(const int* __restrict__ eidx,
                                                int* __restrict__ cnt)
{
  const int e = (int)blockIdx.x * 256 + (int)threadIdx.x;
  atomicAdd(&cnt[eidx[N_EDGES + e]], 1);
}

__global__ __launch_bounds__(1024) void scan_cnt(const int* __restrict__ cnt,
                                                 int* __restrict__ cursor)
{
  __shared__ int part[1024];
  const int t = (int)threadIdx.x;
  const int base = t * 49;
  int s = 0;
#pragma unroll 7
  for (int j = 0; j < 49; ++j) {
    const int idx = base + j;
    if (idx < N_NODES) s += cnt[idx];
  }
  part[t] = s;
  __syncthreads();
  for (int off = 1; off < 1024; off <<= 1) {
    int v = 0;
    if (t >= off) v = part[t - off];
    __syncthreads();
    part[t] += v;
    __syncthreads();
  }
  int run = (t == 0) ? 0 : part[t - 1];
#pragma unroll 7
  for (int j = 0; j < 49; ++j) {
    const int idx = base + j;
    if (idx < N_NODES) { cursor[idx] = run; run += cnt[idx]; }
  }
}

__global__ __launch_bounds__(256) void scatter_perm(
    const int* __restrict__ eidx, const float* __restrict__ ew,
    int* __restrict__ cursor, int* __restrict__ perm,
    float* __restrict__ Cf, int* __restrict__ srcs, int* __restrict__ dsts)
{
  const int e = (int)blockIdx.x * 256 + (int)threadIdx.x;
  const int d = eidx[N_EDGES + e];
  const int pos = atomicAdd(&cursor[d], 1);
  perm[pos] = e;
  Cf[pos]   = 0.5f * (__cosf(ew[e] * 0.31415926535897931f) + 1.0f);
  srcs[pos] = eidx[e];
  dsts[pos] = d;
}

// eattr_s[i][64] bf16 = eattr[perm[i]][k] (k<50), 0-padded. 8 lanes/edge.
__global__ __launch_bounds__(256) void prep_eattr(
    const float* __restrict__ ea, const int* __restrict__ perm,
    unsigned short* __restrict__ out)
{
  const int t = (int)blockIdx.x * 256 + (int)threadIdx.x;
  const int i = t >> 3, j = t & 7;
  const int p = perm[i];
  const float* ap = ea + (size_t)p * 50 + j * 8;
  bf16x8 v;
  if (j < 6) {
    f32x2 a0 = *(const f32x2*)(ap);
    f32x2 a1 = *(const f32x2*)(ap + 2);
    f32x2 a2 = *(const f32x2*)(ap + 4);
    f32x2 a3 = *(const f32x2*)(ap + 6);
    v[0] = (short)f2bf(a0[0]); v[1] = (short)f2bf(a0[1]);
    v[2] = (short)f2bf(a1[0]); v[3] = (short)f2bf(a1[1]);
    v[4] = (short)f2bf(a2[0]); v[5] = (short)f2bf(a2[1]);
    v[6] = (short)f2bf(a3[0]); v[7] = (short)f2bf(a3[1]);
  } else if (j == 6) {
    f32x2 a0 = *(const f32x2*)(ap);
    v[0] = (short)f2bf(a0[0]); v[1] = (short)f2bf(a0[1]);
    v[2] = 0; v[3] = 0; v[4] = 0; v[5] = 0; v[6] = 0; v[7] = 0;
  } else {
    v[0] = 0; v[1] = 0; v[2] = 0; v[3] = 0; v[4] = 0; v[5] = 0; v[6] = 0; v[7] = 0;
  }
  *(bf16x8*)(out + (size_t)i * 64 + j * 8) = v;
}

// ---------------------------------------------------------------------------
// Fused edge pipeline over dst-sorted edges, EBLK=32 edges/block, 4 waves.
// VGPR-lean (target <=64 via launch_bounds(256,8)) -> 8 blocks/CU.
// t_lds [32][256] bf16 = 16 KB, XOR swizzle byte ^= (row&7)<<4.
// ---------------------------------------------------------------------------
__global__ __launch_bounds__(256, 8) void edge_fused(
    const unsigned short* __restrict__ eattr_s,
    const float* __restrict__ Cf,
    const int* __restrict__ srcs, const int* __restrict__ dsts,
    const unsigned short* __restrict__ m1t, const float* __restrict__ m1b,
    const unsigned short* __restrict__ m2t, const float* __restrict__ m2b,
    const unsigned short* __restrict__ h1, float* __restrict__ agg)
{
  __shared__ unsigned short t_lds[EBLK * 256];  // 16 KiB; t, then Wf
  __shared__ float Cs[EBLK];
  __shared__ int s_src[EBLK], s_dst[EBLK + 1];

  const int e0  = (int)blockIdx.x * EBLK;
  const int tid = (int)threadIdx.x;
  if (tid < EBLK) {
    Cs[tid]    = Cf[e0 + tid];
    s_src[tid] = srcs[e0 + tid];
    s_dst[tid] = dsts[e0 + tid];
  }
  if (tid == 0) s_dst[EBLK] = -1;
  __syncthreads();

  const int w = tid >> 6, l = tid & 63, lr = l & 15, g = l >> 4;

  f32x4 acc[2][4];
#pragma unroll
  for (int a = 0; a < 2; ++a)
#pragma unroll
    for (int b = 0; b < 4; ++b) acc[a][b] = f4zero();

  // ---- stage 1: K=50 padded to 64 (m1t zero-padded)
#pragma unroll
  for (int ks = 0; ks < 2; ++ks) {
    const int kb = ks * 32 + g * 8;
    bf16x8 af[2];
#pragma unroll
    for (int mf = 0; mf < 2; ++mf)
      af[mf] = *(const bf16x8*)(eattr_s + (size_t)(e0 + mf * 16 + lr) * 64 + kb);
#pragma unroll
    for (int nf = 0; nf < 4; ++nf) {
      const int col = w * 64 + nf * 16 + lr;
      const bf16x8 bfr = *(const bf16x8*)(m1t + col * 64 + kb);
      __builtin_amdgcn_s_setprio(1);
#pragma unroll
      for (int mf = 0; mf < 2; ++mf)
        acc[mf][nf] = MFMA(af[mf], bfr, acc[mf][nf]);
      __builtin_amdgcn_s_setprio(0);
    }
  }

  // ---- epilogue 1: t = ssp(.) -> t_lds
#pragma unroll
  for (int nf = 0; nf < 4; ++nf) {
    const int col = w * 64 + nf * 16 + lr;
    const float bs = m1b[col];
#pragma unroll
    for (int mf = 0; mf < 2; ++mf)
#pragma unroll
      for (int i = 0; i < 4; ++i) {
        const int r = mf * 16 + g * 4 + i;
        const float x = sspf(acc[mf][nf][i] + bs);
        const int byt = (r * 512 + col * 2) ^ ((r & 7) << 4);
        *(unsigned short*)((char*)t_lds + byt) = f2bf(x);
      }
  }
  __syncthreads();

  // ---- stage 2: K=256
#pragma unroll
  for (int a = 0; a < 2; ++a)
#pragma unroll
    for (int b = 0; b < 4; ++b) acc[a][b] = f4zero();

#pragma unroll
  for (int ks = 0; ks < 8; ++ks) {
    const int kb = ks * 32 + g * 8;
    bf16x8 af[2];
#pragma unroll
    for (int mf = 0; mf < 2; ++mf) {
      const int r = mf * 16 + lr;
      const int byt = (r * 512 + kb * 2) ^ ((r & 7) << 4);
      af[mf] = *(const bf16x8*)((const char*)t_lds + byt);
    }
#pragma unroll
    for (int nf = 0; nf < 4; ++nf) {
      const int col = w * 64 + nf * 16 + lr;
      const bf16x8 bfr = *(const bf16x8*)(m2t + (size_t)col * 256 + kb);
      __builtin_amdgcn_s_setprio(1);
#pragma unroll
      for (int mf = 0; mf < 2; ++mf)
        acc[mf][nf] = MFMA(af[mf], bfr, acc[mf][nf]);
      __builtin_amdgcn_s_setprio(0);
    }
  }

  __syncthreads();  // stage-2 reads complete block-wide before overwrite

  // ---- epilogue 2: Wf = ssp(acc+b2)*C -> t_lds
#pragma unroll
  for (int nf = 0; nf < 4; ++nf) {
    const int col = w * 64 + nf * 16 + lr;
    const float bs = m2b[col];
#pragma unroll
    for (int mf = 0; mf < 2; ++mf) {
#pragma unroll
      for (int i = 0; i < 4; ++i) {
        const int er = mf * 16 + g * 4 + i;
        const float wf = sspf(acc[mf][nf][i] + bs) * Cs[er];
        const int byt = (er * 512 + col * 2) ^ ((er & 7) << 4);
        *(unsigned short*)((char*)t_lds + byt) = f2bf(wf);
      }
    }
  }
  __syncthreads();

  // ---- segmented reduce: thread owns column pair (2cp,2cp+1),
  // rows split 2x16 across thread halves; h1 gather coalesced by column.
  {
    const int half  = tid >> 7;          // 0: rows 0..15, 1: rows 16..31
    const int cp    = tid & 127;
    const int col2  = cp * 2;
    const int rbase = half * 16;
    float s0 = 0.0f, s1 = 0.0f;
#pragma unroll 8
    for (int rr = 0; rr < 16; ++rr) {
      const int r = rbase + rr;
      const int byt = (r * 512 + col2 * 2) ^ ((r & 7) << 4);
      const unsigned int wfp = *(const unsigned int*)((const char*)t_lds + byt);
      const unsigned int xjp =
          *(const unsigned int*)(h1 + (size_t)s_src[r] * 256 + col2);
      s0 += bf2f((unsigned short)(wfp & 0xffff)) * bf2f((unsigned short)(xjp & 0xffff));
      s1 += bf2f((unsigned short)(wfp >> 16)) * bf2f((unsigned short)(xjp >> 16));
      const int d = s_dst[r];
      const bool flush = (rr == 15) || (s_dst[r + 1] != d);
      if (flush) {
        float* ap = agg + (size_t)d * 256 + col2;
        atomicAdd(ap, s0);
        atomicAdd(ap + 1, s1);
        s0 = 0.0f; s1 = 0.0f;
      }
    }
  }
}

// ---------------------------------------------------------------------------
// Transpose + downcast weights
// ---------------------------------------------------------------------------
__global__ __launch_bounds__(256) void prep_weights(
    const float* __restrict__ aw, const float* __restrict__ m1,
    const float* __restrict__ m2, const float* __restrict__ o1,
    const float* __restrict__ o2,
    unsigned short* __restrict__ awt, unsigned short* __restrict__ m1t,
    unsigned short* __restrict__ m2t, unsigned short* __restrict__ o1t,
    unsigned short* __restrict__ o2t)
{
  const int i = (int)blockIdx.x * 256 + (int)threadIdx.x;
  const int c = i >> 8, k = i & 255;
  const int src = k * 256 + c;
  awt[i] = f2bf(aw[src]);
  m2t[i] = f2bf(m2[src]);
  o1t[i] = f2bf(o1[src]);
  o2t[i] = f2bf(o2[src]);
  if (k < 64) m1t[c * 64 + k] = (k < 50) ? f2bf(m1[k * 256 + c]) : (unsigned short)0;
}

extern "C" void kernel_launch(void* const* d_in, const int* in_sizes, int n_in,
                              void* d_out, int out_size, void* d_ws, size_t ws_size,
                              hipStream_t stream)
{
  const float* h    = (const float*)d_in[0];
  const int*   eidx = (const int*)d_in[1];
  const float* ew   = (const float*)d_in[2];
  const float* ea   = (const float*)d_in[3];
  const float* awW  = (const float*)d_in[4];
  const float* awb  = (const float*)d_in[5];
  const float* m1W  = (const float*)d_in[6];
  const float* m1b  = (const float*)d_in[7];
  const float* m2W  = (const float*)d_in[8];
  const float* m2b  = (const float*)d_in[9];
  const float* o1W  = (const float*)d_in[10];
  const float* o1b  = (const float*)d_in[11];
  const float* o2W  = (const float*)d_in[12];
  const float* o2b  = (const float*)d_in[13];

  char* ws = (char*)d_ws;
  unsigned short* h1  = (unsigned short*)ws;                  // 25,600,000 B
  float*          agg = (float*)(ws + 25600000);              // 51,200,000 B
  char* wbase = ws + 25600000 + 51200000;                     // 76,800,000
  unsigned short* awt = (unsigned short*)wbase;               // 131072 B
  unsigned short* m2t = awt + 65536;                          // 131072 B
  unsigned short* o1t = m2t + 65536;                          // 131072 B
  unsigned short* o2t = o1t + 65536;                          // 131072 B
  unsigned short* m1t = o2t + 65536;                          // 32768 B
  char* p0 = wbase + 4 * 131072 + 32768;                      // 77,357,056
  int* cnt    = (int*)p0;                                     // 200,000 B
  int* cursor = cnt + N_NODES;                                // 200,000 B
  int* perm   = cursor + N_NODES;                             // 3,200,000 B
  char* p1 = p0 + 400000 + 3200000;                           // 80,957,056
  float* Cf   = (float*)p1;                                   // 3,200,000 B
  int*   srcs = (int*)(p1 + 3200000);                         // 3,200,000 B
  int*   dsts = (int*)(p1 + 6400000);                         // 3,200,000 B
  unsigned short* eattr_s = (unsigned short*)(p1 + 9600000);  // 102,400,000 B

  hipMemsetAsync(agg, 0, (size_t)N_NODES * 256 * 4, stream);
  hipMemsetAsync(cnt, 0, (size_t)N_NODES * 4, stream);

  prep_weights<<<256, 256, 0, stream>>>(awW, m1W, m2W, o1W, o2W,
                                        awt, m1t, m2t, o1t, o2t);
  hist_dst<<<N_EDGES / 256, 256, 0, stream>>>(eidx, cnt);
  scan_cnt<<<1, 1024, 0, stream>>>(cnt, cursor);
  scatter_perm<<<N_EDGES / 256, 256, 0, stream>>>(eidx, ew, cursor, perm,
                                                  Cf, srcs, dsts);
  prep_eattr<<<N_EDGES * 8 / 256, 256, 0, stream>>>(ea, perm, eattr_s);

  // h1 = h @ aw_W + aw_b
  gemm_k256<1, 0, 0><<<(N_NODES + 63) / 64, 256, 0, stream>>>(h, awt, awb, h1, N_NODES);

  edge_fused<<<N_EDGES / EBLK, 256, 0, stream>>>(
      eattr_s, Cf, srcs, dsts, m1t, m1b, m2t, m2b, h1, agg);

  // o = ssp(agg @ o1_W + o1_b)   (into h1's buffer)
  gemm_k256<1, 1, 0><<<(N_NODES + 63) / 64, 256, 0, stream>>>(agg, o1t, o1b, h1, N_NODES);
  // out = o @ o2_W + o2_b
  gemm_k256<0, 0, 1><<<(N_NODES + 63) / 64, 256, 0, stream>>>(h1, o2t, o2b, d_out, N_NODES);
}